// Round 9
// baseline (149.833 us; speedup 1.0000x reference)
//
#include <hip/hip_runtime.h>
#include <hip/hip_bf16.h>
#include <stdint.h>

// RoPE self-attention, bf16-MFMA pipeline.
// B=2 L=2048 D=1024 H=16 DK=64. GEMM1 fuses bias+RoPE+pack (Q,K) and
// bias+transpose (V), with LDS-vectorized epilogue stores. Attention:
// 32x32x16 MFMA, in-register P via cvt_pk+permlane32_swap, 3-buffer KV
// staging with counted vmcnt. Q pre-scaled by 0.125*log2(e) (exp2 domain).

typedef __attribute__((ext_vector_type(8)))  short bf16x8;   // MFMA A/B frag
typedef __attribute__((ext_vector_type(4)))  float f32x4;    // 16x16 C/D frag
typedef __attribute__((ext_vector_type(16))) float f32x16;   // 32x32 C/D frag
typedef __attribute__((ext_vector_type(4)))  short short4v;
typedef __attribute__((ext_vector_type(4)))  unsigned int u32x4;

#define DEV static __device__ __forceinline__

DEV short f2bf(float f) {            // RNE f32->bf16
  uint32_t u = __builtin_bit_cast(uint32_t, f);
  u += 0x7FFFu + ((u >> 16) & 1u);
  return (short)(u >> 16);
}
DEV float bf2f(short s) {
  return __builtin_bit_cast(float, ((uint32_t)(uint16_t)s) << 16);
}
DEV uint32_t pkbf(float a, float b) { // packed f32x2 -> bf16x2 (v_cvt_pk path)
  __hip_bfloat162 h = __float22bfloat162_rn(make_float2(a, b));
  uint32_t u;
  __builtin_memcpy(&u, &h, 4);
  return u;
}
// v_permlane32_swap_b32 vdst, vsrc: dst.upper <-> src.lower (verified R7)
DEV void pl32swap(uint32_t &dst, uint32_t &src) {
  asm volatile("v_permlane32_swap_b32 %0, %1" : "+v"(dst), "+v"(src));
}

#define AS1 __attribute__((address_space(1)))
#define AS3 __attribute__((address_space(3)))
#define GLOAD_LDS16(gp, lp) \
  __builtin_amdgcn_global_load_lds((const AS1 void*)(gp), (AS3 void*)(lp), 16, 0, 0)

// ---------------------------------------------------------------- f32 -> bf16
__global__ void k_cvt_bf16(const float* __restrict__ in, short* __restrict__ out, int n4) {
  int i = blockIdx.x * 256 + threadIdx.x;
  if (i >= n4) return;
  float4 v = reinterpret_cast<const float4*>(in)[i];
  short4v o = { f2bf(v.x), f2bf(v.y), f2bf(v.z), f2bf(v.w) };
  reinterpret_cast<short4v*>(out)[i] = o;
}

// -------------------------------------------------------------- GEMM template
// body: C128x128 = A[M][K] @ Bt[N][K]^T, BK=64, 4 waves 2x2, m97 structure.
// Lds is one flat 32KB region (As = Lds, Bs = Lds+8192) so epilogues can
// reuse it per-wave after the final barrier.
#define GEMM_BODY(A_, Bt_, K_)                                              \
  __shared__ short Lds[2 * 128 * 64];                                       \
  short* As = Lds;                                                          \
  short* Bs = Lds + 128 * 64;                                               \
  const int tid = threadIdx.x;                                              \
  const int lane = tid & 63;                                                \
  const int wid  = tid >> 6;                                                \
  const int lq = lane & 15, lg = lane >> 4;                                 \
  const int wr = wid >> 1, wc = wid & 1;                                    \
  const int m0 = blockIdx.y * 128;                                          \
  const int n0 = blockIdx.x * 128;                                          \
  f32x4 acc[4][4];                                                          \
  _Pragma("unroll")                                                         \
  for (int i = 0; i < 4; ++i)                                               \
    _Pragma("unroll")                                                       \
    for (int j = 0; j < 4; ++j) acc[i][j] = (f32x4){0.f, 0.f, 0.f, 0.f};    \
  const int KT = (K_) >> 6;                                                 \
  for (int kt = 0; kt < KT; ++kt) {                                         \
    const short* Ag = (A_)  + (size_t)m0 * (K_) + kt * 64;                  \
    const short* Bg = (Bt_) + (size_t)n0 * (K_) + kt * 64;                  \
    _Pragma("unroll")                                                       \
    for (int p = 0; p < 4; ++p) {                                           \
      int f = p * 256 + tid;                                                \
      int row = f >> 3, ce = (f & 7) * 8;                                   \
      GLOAD_LDS16(Ag + (size_t)row * (K_) + ce, As + f * 8);                \
      GLOAD_LDS16(Bg + (size_t)row * (K_) + ce, Bs + f * 8);                \
    }                                                                       \
    asm volatile("s_waitcnt vmcnt(0)" ::: "memory");                        \
    __syncthreads();                                                        \
    _Pragma("unroll")                                                       \
    for (int kk = 0; kk < 2; ++kk) {                                        \
      bf16x8 af[4], bfr[4];                                                 \
      _Pragma("unroll")                                                     \
      for (int i = 0; i < 4; ++i)                                           \
        af[i]  = *reinterpret_cast<const bf16x8*>(                          \
            &As[(wr*64 + i*16 + lq) * 64 + kk*32 + lg*8]);                  \
      _Pragma("unroll")                                                     \
      for (int j = 0; j < 4; ++j)                                           \
        bfr[j] = *reinterpret_cast<const bf16x8*>(                          \
            &Bs[(wc*64 + j*16 + lq) * 64 + kk*32 + lg*8]);                  \
      _Pragma("unroll")                                                     \
      for (int i = 0; i < 4; ++i)                                           \
        _Pragma("unroll")                                                   \
        for (int j = 0; j < 4; ++j)                                         \
          acc[i][j] = __builtin_amdgcn_mfma_f32_16x16x32_bf16(              \
              af[i], bfr[j], acc[i][j], 0, 0, 0);                           \
    }                                                                       \
    __syncthreads();                                                        \
  }

// ---------------- GEMM1: x @ Wqkv^T + b, fused RoPE(Q,K-scaled) + V-transpose
// Outputs: Qb,Kb [bh][l][64] bf16 (Q pre-scaled 0.125*log2e), Vt [bh][64][l].
// C/D layout col=lane&15, row=(lane>>4)*4+r [m89]; RoPE pair (d,d+32) =
// acc cols (j, j+2) -- same lane. Epilogue routes through per-wave 8KB LDS
// (reusing staging LDS after the final barrier) to emit 16B coalesced stores.
__global__ __launch_bounds__(256) void k_gemm_qkv(
    const short* __restrict__ A, const short* __restrict__ Bt,
    const float* __restrict__ bias,
    const float* __restrict__ cosb, const float* __restrict__ sinb,
    short* __restrict__ Qb, short* __restrict__ Kb, short* __restrict__ Vt)
{
  GEMM_BODY(A, Bt, 1024)

  short* Ep = Lds + wid * 4096;                // per-wave 8KB scratch
  const int cglob = n0 + wc * 64;              // head base col in [0,3072)
  if (cglob < 2048) {                          // ---- Q or K: bias + RoPE
    const bool isq = (cglob < 1024);
    const float QS = isq ? 0.125f * 1.4426950408889634f : 1.0f;
    short* dst = isq ? Qb : Kb;
    const int h = (cglob & 1023) >> 6;
    const float b0 = bias[cglob + lq],      b2 = bias[cglob + 32 + lq];
    const float b1 = bias[cglob + 16 + lq], b3 = bias[cglob + 48 + lq];
    // compute + scalar LDS writes, l-major Ep[l][64d] (2 lanes/bank: free)
    #pragma unroll
    for (int i = 0; i < 4; ++i) {
      #pragma unroll
      for (int r = 0; r < 4; ++r) {
        int lloc = i*16 + lg*4 + r;
        int rg = m0 + wr*64 + lloc;                // global row = b*2048 + l
        float c0 = cosb[(size_t)rg * 32 + lq];
        float s0 = sinb[(size_t)rg * 32 + lq];
        float c1 = cosb[(size_t)rg * 32 + 16 + lq];
        float s1 = sinb[(size_t)rg * 32 + 16 + lq];
        float x1 = acc[i][0][r] + b0, x2 = acc[i][2][r] + b2;   // d = lq
        Ep[lloc*64 + lq]      = f2bf((x1 * c0 - x2 * s0) * QS);
        Ep[lloc*64 + 32 + lq] = f2bf((x1 * s0 + x2 * c0) * QS);
        float y1 = acc[i][1][r] + b1, y2 = acc[i][3][r] + b3;   // d = 16+lq
        Ep[lloc*64 + 16 + lq] = f2bf((y1 * c1 - y2 * s1) * QS);
        Ep[lloc*64 + 48 + lq] = f2bf((y1 * s1 + y2 * c1) * QS);
      }
    }
    // vector read-back + 16B coalesced stores (wave-private region)
    #pragma unroll
    for (int p = 0; p < 8; ++p) {
      int f = p * 64 + lane;
      int lloc = f >> 3, d0 = (f & 7) * 8;
      int rg = m0 + wr*64 + lloc;
      int bi = rg >> 11, ll = rg & 2047;
      bf16x8 v = *reinterpret_cast<const bf16x8*>(&Ep[lloc*64 + d0]);
      *reinterpret_cast<bf16x8*>(
          &dst[((size_t)(bi * 16 + h) * 2048 + ll) * 64 + d0]) = v;
    }
  } else {                                     // ---- V: bias + transpose
    const int h = (cglob - 2048) >> 6;
    // b64 LDS writes, d-major Ep[d][64l] with XOR swizzle l ^= (d&7)<<3
    #pragma unroll
    for (int i = 0; i < 4; ++i) {
      int lloc = i*16 + lg*4;                      // 4 consecutive l
      #pragma unroll
      for (int j = 0; j < 4; ++j) {
        int d = j * 16 + lq;
        float bv = bias[cglob + d];
        short4v pk4 = { f2bf(acc[i][j][0] + bv), f2bf(acc[i][j][1] + bv),
                        f2bf(acc[i][j][2] + bv), f2bf(acc[i][j][3] + bv) };
        *reinterpret_cast<short4v*>(
            &Ep[d*64 + (lloc ^ ((d & 7) << 3))]) = pk4;
      }
    }
    // vector read-back: position lc holds l = lc ^ ((d&7)<<3)
    #pragma unroll
    for (int p = 0; p < 8; ++p) {
      int f = p * 64 + lane;
      int d = f >> 3, lc = (f & 7) * 8;
      bf16x8 v = *reinterpret_cast<const bf16x8*>(&Ep[d*64 + lc]);
      int lreal = lc ^ ((d & 7) << 3);
      int rg = m0 + wr*64 + lreal;                 // 8-aligned run of l
      int bi = rg >> 11, ll = rg & 2047;
      *reinterpret_cast<bf16x8*>(
          &Vt[((size_t)(bi * 16 + h) * 64 + d) * 2048 + ll]) = v;
    }
  }
}

// -------------------------------------------- GEMM2: AO @ Wout^T + b, f32 out
__global__ __launch_bounds__(256) void k_gemm_out(
    const short* __restrict__ A, const short* __restrict__ Bt,
    const float* __restrict__ bias, float* __restrict__ C)
{
  GEMM_BODY(A, Bt, 1024)
  const int N = 1024;
  #pragma unroll
  for (int i = 0; i < 4; ++i) {
    int rbase = m0 + wr*64 + i*16 + lg*4;
    #pragma unroll
    for (int j = 0; j < 4; ++j) {
      int col = n0 + wc*64 + j*16 + lq;
      float bv = bias[col];
      #pragma unroll
      for (int r = 0; r < 4; ++r)
        C[(size_t)(rbase + r) * N + col] = acc[i][j][r] + bv;
    }
  }
}

// ------------------------------------------------------------ flash attention
// 4 waves/block, 32 q-rows/wave (32x32x16 MFMA), KVBLK=64. K/V staged in LDS,
// 3-buffer + counted vmcnt (T4): stage(t+2) issued at iter t, wait vmcnt(4)
// keeps stage(t+1)'s 4 loads in flight across the barrier -> ~2 compute
// phases of latency cover. Raw s_barrier (no vmcnt(0) drain). XOR-swizzled
// tiles via pre-swizzled global source (rule #21). Swapped QK^T, exp2-direct
// softmax, in-register P via cvt_pk+permlane32_swap (T12).
__global__ __launch_bounds__(256) void k_attn(
    const short* __restrict__ Q, const short* __restrict__ Kb,
    const short* __restrict__ Vt, short* __restrict__ AO)
{
  __shared__ short Ks[3][64 * 64];   // 8KB x3, swizzled, rows = kv
  __shared__ short Vs[3][64 * 64];   // 8KB x3, swizzled, rows = d
  const int tid = threadIdx.x;
  const int lane = tid & 63;
  const int wid  = tid >> 6;         // 0..3
  const int Lq = lane & 31;          // q-col / d-col / kv-row
  const int h  = lane >> 5;          // half-select
  const int bh = blockIdx.y;
  const int q0 = blockIdx.x * 128 + wid * 32;
  const int b = bh >> 4, hh = bh & 15;

  const short* Qp = Q  + ((size_t)bh * 2048 + q0 + Lq) * 64;
  const short* Kp = Kb + (size_t)bh * 2048 * 64;
  const short* Vp = Vt + (size_t)bh * 64 * 2048;

  // stage 64x64 bf16 tile: 512 chunks of 16B, 2 per thread (256 threads)
  // = 4 global_load_lds per thread. LDS linear dest; source pre-swizzled.
  #define STAGE_KV(c, t) do {                                              \
    const short* Kg_ = Kp + (size_t)(t) * 64 * 64;                         \
    const short* Vg_ = Vp + (size_t)(t) * 64;                              \
    _Pragma("unroll")                                                      \
    for (int p_ = 0; p_ < 2; ++p_) {                                       \
      int f_ = p_ * 256 + tid;                                             \
      int row_ = f_ >> 3;                                                  \
      int sch_ = (f_ & 7) ^ (row_ & 7);                                    \
      GLOAD_LDS16(Kg_ + row_ * 64 + sch_ * 8,            &Ks[c][f_ * 8]);  \
      GLOAD_LDS16(Vg_ + (size_t)row_ * 2048 + sch_ * 8,  &Vs[c][f_ * 8]);  \
    }                                                                      \
  } while (0)

  // Q B-frags (registers): frag[ks] = Q[q0+Lq][ks*16 + h*8 .. +8]
  bf16x8 qf[4];
  #pragma unroll
  for (int ks = 0; ks < 4; ++ks)
    qf[ks] = *reinterpret_cast<const bf16x8*>(Qp + ks * 16 + h * 8);

  f32x16 o[2];
  #pragma unroll
  for (int nd = 0; nd < 2; ++nd)
    #pragma unroll
    for (int r = 0; r < 16; ++r) o[nd][r] = 0.f;
  float la0 = 0.f, la1 = 0.f, la2 = 0.f, la3 = 0.f;

  STAGE_KV(0, 0);
  STAGE_KV(1, 1);
  int cur = 0;

  for (int kvt = 0; kvt < 32; ++kvt) {
    // wait for stage(kvt): stage(kvt+1)'s 4 loads stay in flight
    if (kvt < 31) asm volatile("s_waitcnt vmcnt(4)" ::: "memory");
    else          asm volatile("s_waitcnt vmcnt(0)" ::: "memory");
    __builtin_amdgcn_s_barrier();    // all waves done reading buf[cur+2 mod 3]
    if (kvt + 2 < 32) {
      int nb = cur + 2; if (nb >= 3) nb -= 3;
      STAGE_KV(nb, kvt + 2);         // its buffer last read at iter kvt-1
    }

    // ---- QK^T: S^T[kv][q], A = K-tile rows (swizzled read), B = qf
    f32x16 s[2];
    #pragma unroll
    for (int mb = 0; mb < 2; ++mb)
      #pragma unroll
      for (int r = 0; r < 16; ++r) s[mb][r] = 0.f;
    #pragma unroll
    for (int ks = 0; ks < 4; ++ks)
      #pragma unroll
      for (int mb = 0; mb < 2; ++mb) {
        bf16x8 kf = *reinterpret_cast<const bf16x8*>(
            &Ks[cur][(mb*32 + Lq) * 64 + (((ks*2 + h) ^ (Lq & 7)) * 8)]);
        s[mb] = __builtin_amdgcn_mfma_f32_32x32x16_bf16(kf, qf[ks], s[mb], 0, 0, 0);
      }
    // ---- softmax (exp2-direct) + pack to bf16 pairs
    uint32_t pk[2][8];
    #pragma unroll
    for (int mb = 0; mb < 2; ++mb)
      #pragma unroll
      for (int j = 0; j < 8; ++j) {
        float pa_ = __builtin_amdgcn_exp2f(s[mb][2*j]);
        float pb_ = __builtin_amdgcn_exp2f(s[mb][2*j + 1]);
        if ((j & 3) == 0) la0 += pa_ + pb_;
        else if ((j & 3) == 1) la1 += pa_ + pb_;
        else if ((j & 3) == 2) la2 += pa_ + pb_;
        else la3 += pa_ + pb_;
        pk[mb][j] = pkbf(pa_, pb_);
      }
    // ---- rebuild PV A-frags in-register + PV
    #pragma unroll
    for (int ks = 0; ks < 4; ++ks) {
      const int mb = ks >> 1, be = (ks & 1) * 4;
      uint32_t w0 = pk[mb][be + 0], w2 = pk[mb][be + 2];
      uint32_t w1 = pk[mb][be + 1], w3 = pk[mb][be + 3];
      pl32swap(w0, w2);
      pl32swap(w1, w3);
      u32x4 paw = { w0, w1, w2, w3 };
      bf16x8 pa = __builtin_bit_cast(bf16x8, paw);
      #pragma unroll
      for (int nd = 0; nd < 2; ++nd) {
        bf16x8 vf = *reinterpret_cast<const bf16x8*>(
            &Vs[cur][(nd*32 + Lq) * 64 + (((ks*2 + h) ^ (Lq & 7)) * 8)]);
        o[nd] = __builtin_amdgcn_mfma_f32_32x32x16_bf16(pa, vf, o[nd], 0, 0, 0);
      }
    }
    cur = (cur == 2) ? 0 : cur + 1;
  }

  // ---- epilogue: l reduce + normalize + store
  float l_part = (la0 + la1) + (la2 + la3);
  l_part += __shfl_xor(l_part, 32, 64);
  float inv = 1.f / l_part;
  #pragma unroll
  for (int r = 0; r < 16; ++r) {
    int qrow = (r & 3) + 8 * (r >> 2) + 4 * h;
    float ir = __shfl(inv, qrow, 64);
    size_t rowb = ((size_t)b * 2048 + q0 + qrow) * 1024 + hh * 64;
    AO[rowb + Lq]      = f2bf(o[0][r] * ir);
    AO[rowb + 32 + Lq] = f2bf(o[1][r] * ir);
  }
  #undef STAGE_KV
}

// ----------------------------------------------------------------------------
extern "C" void kernel_launch(void* const* d_in, const int* in_sizes, int n_in,
                              void* d_out, int out_size, void* d_ws, size_t ws_size,
                              hipStream_t stream) {
  (void)in_sizes; (void)n_in; (void)out_size; (void)ws_size;
  const float* x    = (const float*)d_in[0];
  const float* rc   = (const float*)d_in[1];
  const float* rs   = (const float*)d_in[2];
  const float* Wqkv = (const float*)d_in[3];
  const float* bqkv = (const float*)d_in[4];
  const float* Wout = (const float*)d_in[5];
  const float* bout = (const float*)d_in[6];
  float* out = (float*)d_out;

  char* ws = (char*)d_ws;
  short* xb  = (short*)(ws);              // x bf16        [4096][1024]  8.39MB
  short* wqb = (short*)(ws + 8388608);    // Wqkv bf16     [3072][1024]  6.29MB
  short* wob = (short*)(ws + 14680064);   // Wout bf16     [1024][1024]  2.10MB
  short* Qb  = (short*)(ws + 16777216);   // Q roped+scaled[32][2048][64] 8.39MB
  short* Kb  = (short*)(ws + 25165824);   // K roped       [32][2048][64] 8.39MB
  short* Vt  = (short*)(ws + 33554432);   // V transposed  [32][64][2048] 8.39MB
  short* AO  = (short*)(ws + 41943040);   // attn out bf16 [4096][1024]  8.39MB
                                          // total 50.3MB

  k_cvt_bf16<<<4096, 256, 0, stream>>>(x,    xb,  1048576);
  k_cvt_bf16<<<3072, 256, 0, stream>>>(Wqkv, wqb, 786432);
  k_cvt_bf16<<<1024, 256, 0, stream>>>(Wout, wob, 262144);
  k_gemm_qkv<<<dim3(24, 32), 256, 0, stream>>>(xb, wqb, bqkv, rc, rs, Qb, Kb, Vt);
  k_attn<<<dim3(16, 32), 256, 0, stream>>>(Qb, Kb, Vt, AO);
  k_gemm_out<<<dim3(8, 32), 256, 0, stream>>>(AO, wob, bout, out);
}